// Round 1
// baseline (321.798 us; speedup 1.0000x reference)
//
#include <hip/hip_runtime.h>
#include <stdint.h>

#define B_    32768
#define C_    64
#define D_    8
#define K15_  15
#define K16_  16
#define OUT_  512

// workspace layout (bytes)
#define AMAP_OFF  0
#define AMAP_SZ   32768                 // uint8 argmax per 15-bit code
#define IDX_OFF   (AMAP_OFF + AMAP_SZ)  // 32768
#define IDX_SZ    (B_ * C_)             // 2 MB, uint8 idx per (b,c)
#define PC_OFF    (IDX_OFF + IDX_SZ)    // 2,129,920
#define PC_SZ     (B_ * 32)             // 1 MB, uint8 pair code per (b,pair)
#define PTAB_OFF  (PC_OFF + PC_SZ)      // 3,178,496
#define PTAB_SZ   (32 * 256 * 512 * 4)  // 16,777,216  P[pair][t0t1][512]
#define WS_NEED   ((size_t)PTAB_OFF + PTAB_SZ)
#define WS_NEED_FALLBACK ((size_t)PC_OFF)

// ---------------------------------------------------------------------------
// Kernel 1: amap[code] = argmax_j sum_k (+-1)*H[k][j], fp64 for tie safety.
// 32768 codes, trivial.
// ---------------------------------------------------------------------------
__global__ __launch_bounds__(256) void k_amap(const float* __restrict__ H,
                                              uint8_t* __restrict__ amap) {
    int code = blockIdx.x * 256 + threadIdx.x;
    double h[K16_];
#pragma unroll
    for (int j = 0; j < K16_; ++j) h[j] = 0.0;
#pragma unroll
    for (int k = 0; k < K15_; ++k) {
        double s = ((code >> k) & 1) ? 1.0 : -1.0;
#pragma unroll
        for (int j = 0; j < K16_; ++j) h[j] += s * (double)H[k * K16_ + j];
    }
    // first-max argmax (matches np.argmax)
    double best = h[0];
    int bi = 0;
#pragma unroll
    for (int j = 1; j < K16_; ++j) {
        if (h[j] > best) { best = h[j]; bi = j; }
    }
    amap[code] = (uint8_t)bi;
}

// ---------------------------------------------------------------------------
// Kernel 2: per (b,c): p[k] = x[b,c,:].S[c,:,k] - T[c,k] (fp64), sign bits ->
// 15-bit code -> amap -> idx. Writes idx[b][c] and pair codes pc[b][p].
// Thread = (b,c), c = lane. S,T staged in LDS (S padded to 121 floats/channel
// so lane-stride 121 covers all 32 banks -> conflict-free).
// ---------------------------------------------------------------------------
__global__ __launch_bounds__(256) void k_codes(const float* __restrict__ x,
                                               const float* __restrict__ S,
                                               const float* __restrict__ T,
                                               const uint8_t* __restrict__ amap,
                                               uint8_t* __restrict__ idxo,
                                               uint8_t* __restrict__ pco) {
    __shared__ float Sl[C_ * 121];
    __shared__ float Tl[C_ * K15_];
    for (int i = threadIdx.x; i < C_ * 120; i += 256) {
        int c = i / 120;
        int r = i - c * 120;
        Sl[c * 121 + r] = S[i];
    }
    for (int i = threadIdx.x; i < C_ * K15_; i += 256) Tl[i] = T[i];
    __syncthreads();

    int gid = blockIdx.x * 256 + threadIdx.x;
    int b = gid >> 6;
    int c = gid & 63;

    const float4* xr = (const float4*)(x + (size_t)b * 512 + c * 8);
    float4 a0 = xr[0];
    float4 a1 = xr[1];
    double xd[8] = {a0.x, a0.y, a0.z, a0.w, a1.x, a1.y, a1.z, a1.w};

    const float* Sc = &Sl[c * 121];
    const float* Tc = &Tl[c * K15_];

    unsigned code = 0;
#pragma unroll
    for (int k = 0; k < K15_; ++k) {
        double p = -(double)Tc[k];
#pragma unroll
        for (int d = 0; d < D_; ++d) p = fma(xd[d], (double)Sc[d * K15_ + k], p);
        code |= (p > 0.0) ? (1u << k) : 0u;
    }
    unsigned idx = amap[code];
    idxo[gid] = (uint8_t)idx;

    // pair code: even lane combines with its odd neighbor (same wave)
    unsigned other = (unsigned)__shfl_down((int)idx, 1);
    if (!(c & 1)) pco[b * 32 + (c >> 1)] = (uint8_t)((idx << 4) | other);
}

// ---------------------------------------------------------------------------
// Kernel 3: pair table P[p][t0*16+t1][j] = LUT[2p][t0][j] + LUT[2p+1][t1][j]
// ---------------------------------------------------------------------------
__global__ __launch_bounds__(256) void k_pairs(const float* __restrict__ LUT,
                                               float* __restrict__ P) {
    int gid = blockIdx.x * 256 + threadIdx.x;  // over float4 elements
    int j4 = gid & 127;
    int q = (gid >> 7) & 255;
    int p = gid >> 15;
    const float4* L4 = (const float4*)LUT;
    float4 u = L4[(size_t)((p * 2) * 16 + (q >> 4)) * 128 + j4];
    float4 v = L4[(size_t)((p * 2 + 1) * 16 + (q & 15)) * 128 + j4];
    float4 w;
    w.x = u.x + v.x; w.y = u.y + v.y; w.z = u.z + v.z; w.w = u.w + v.w;
    ((float4*)P)[gid] = w;
}

// ---------------------------------------------------------------------------
// Kernel 4: out[b][:] = sum over 32 pairs of P[p][pc[b][p]][:]
// Block = 256 threads: j4 = tid&127 (covers 512 floats as float4),
// sub = tid>>7 selects row-half. Each thread accumulates 8 rows.
// Row pointers are wave-uniform (readfirstlane) -> coalesced 1KB loads.
// ---------------------------------------------------------------------------
__global__ __launch_bounds__(256) void k_main_pair(const uint8_t* __restrict__ pc,
                                                   const float* __restrict__ P,
                                                   float* __restrict__ out) {
    int j4 = threadIdx.x & 127;
    int sub = threadIdx.x >> 7;
    int b0 = blockIdx.x * 16 + sub * 8;
    const float4* P4 = (const float4*)P;
    for (int r = 0; r < 8; ++r) {
        int b = b0 + r;
        const uint32_t* pw = (const uint32_t*)(pc + (size_t)b * 32);
        float4 acc;
        acc.x = 0.f; acc.y = 0.f; acc.z = 0.f; acc.w = 0.f;
#pragma unroll
        for (int i = 0; i < 8; ++i) {
            uint32_t w = __builtin_amdgcn_readfirstlane(pw[i]);
#pragma unroll
            for (int t = 0; t < 4; ++t) {
                int p = i * 4 + t;
                uint32_t codev = (w >> (8 * t)) & 0xFFu;
                float4 v = P4[(size_t)((p << 8) + codev) * 128 + j4];
                acc.x += v.x; acc.y += v.y; acc.z += v.z; acc.w += v.w;
            }
        }
        ((float4*)(out + (size_t)b * 512))[j4] = acc;
    }
}

// Fallback (small ws): direct 64-channel gather from LUT (2x L2 traffic).
__global__ __launch_bounds__(256) void k_main_direct(const uint8_t* __restrict__ idx,
                                                     const float* __restrict__ LUT,
                                                     float* __restrict__ out) {
    int j4 = threadIdx.x & 127;
    int sub = threadIdx.x >> 7;
    int b0 = blockIdx.x * 16 + sub * 8;
    const float4* L4 = (const float4*)LUT;
    for (int r = 0; r < 8; ++r) {
        int b = b0 + r;
        const uint32_t* iw = (const uint32_t*)(idx + (size_t)b * 64);
        float4 acc;
        acc.x = 0.f; acc.y = 0.f; acc.z = 0.f; acc.w = 0.f;
#pragma unroll
        for (int i = 0; i < 16; ++i) {
            uint32_t w = __builtin_amdgcn_readfirstlane(iw[i]);
#pragma unroll
            for (int t = 0; t < 4; ++t) {
                int c = i * 4 + t;
                uint32_t codev = (w >> (8 * t)) & 0xFu;
                float4 v = L4[(size_t)(c * 16 + codev) * 128 + j4];
                acc.x += v.x; acc.y += v.y; acc.z += v.z; acc.w += v.w;
            }
        }
        ((float4*)(out + (size_t)b * 512))[j4] = acc;
    }
}

extern "C" void kernel_launch(void* const* d_in, const int* in_sizes, int n_in,
                              void* d_out, int out_size, void* d_ws, size_t ws_size,
                              hipStream_t stream) {
    const float* x   = (const float*)d_in[0];
    const float* S   = (const float*)d_in[1];
    const float* H   = (const float*)d_in[2];
    const float* T   = (const float*)d_in[3];
    const float* LUT = (const float*)d_in[4];
    float* out = (float*)d_out;

    uint8_t* ws = (uint8_t*)d_ws;
    uint8_t* amap = ws + AMAP_OFF;
    uint8_t* idxb = ws + IDX_OFF;
    uint8_t* pcb  = ws + PC_OFF;
    float* P      = (float*)(ws + PTAB_OFF);

    bool use_pairs = ws_size >= WS_NEED;

    // 1) code -> argmax table (32K entries)
    hipLaunchKernelGGL(k_amap, dim3(32768 / 256), dim3(256), 0, stream, H, amap);
    // 2) pair-sum table (independent of amap; stream-serial anyway)
    if (use_pairs) {
        hipLaunchKernelGGL(k_pairs, dim3((32 * 256 * 128) / 256), dim3(256), 0,
                           stream, LUT, P);
    }
    // 3) per (b,c) codes/indices
    hipLaunchKernelGGL(k_codes, dim3((B_ * C_) / 256), dim3(256), 0, stream,
                       x, S, T, amap, idxb, pcb);
    // 4) gather-accumulate
    if (use_pairs) {
        hipLaunchKernelGGL(k_main_pair, dim3(B_ / 16), dim3(256), 0, stream,
                           pcb, P, out);
    } else {
        hipLaunchKernelGGL(k_main_direct, dim3(B_ / 16), dim3(256), 0, stream,
                           idxb, LUT, out);
    }
}

// Round 2
// 225.396 us; speedup vs baseline: 1.4277x; 1.4277x over previous
//
#include <hip/hip_runtime.h>
#include <stdint.h>

#define B_    32768
#define C_    64
#define D_    8
#define K15_  15
#define K16_  16
#define OUT_  512

typedef _Float16 half8 __attribute__((ext_vector_type(8)));

// workspace layout (bytes)
#define AMAP_OFF  0
#define AMAP_SZ   32768                 // uint8 argmax per 15-bit code
#define IDX_OFF   (AMAP_OFF + AMAP_SZ)  // 32768
#define IDX_SZ    (B_ * C_)             // 2 MB, uint8 idx per (b,c)
#define PC_OFF    (IDX_OFF + IDX_SZ)    // 2,129,920
#define PC_SZ     (B_ * 32)             // 1 MB, uint8 pair code per (b,pair)
#define PTAB_OFF  (PC_OFF + PC_SZ)      // 3,178,496 (16B aligned)
#define PTAB_SZ   (32 * 256 * 512 * 2)  // 8,388,608  P[pair][t0t1][512] fp16
#define WS_NEED   ((size_t)PTAB_OFF + PTAB_SZ)

// ---------------------------------------------------------------------------
// Kernel 1: amap[code] = argmax_j sum_k (+-1)*H[k][j], fp64 for tie safety.
// ---------------------------------------------------------------------------
__global__ __launch_bounds__(256) void k_amap(const float* __restrict__ H,
                                              uint8_t* __restrict__ amap) {
    int code = blockIdx.x * 256 + threadIdx.x;
    double h[K16_];
#pragma unroll
    for (int j = 0; j < K16_; ++j) h[j] = 0.0;
#pragma unroll
    for (int k = 0; k < K15_; ++k) {
        double s = ((code >> k) & 1) ? 1.0 : -1.0;
#pragma unroll
        for (int j = 0; j < K16_; ++j) h[j] += s * (double)H[k * K16_ + j];
    }
    double best = h[0];
    int bi = 0;
#pragma unroll
    for (int j = 1; j < K16_; ++j) {
        if (h[j] > best) { best = h[j]; bi = j; }
    }
    amap[code] = (uint8_t)bi;
}

// ---------------------------------------------------------------------------
// Kernel 2: per (b,c): p[k] = x[b,c,:].S[c,:,k] - T[c,k] (fp64), sign bits ->
// 15-bit code -> amap -> idx. Writes idx[b][c] and pair codes pc[b][p].
// ---------------------------------------------------------------------------
__global__ __launch_bounds__(256) void k_codes(const float* __restrict__ x,
                                               const float* __restrict__ S,
                                               const float* __restrict__ T,
                                               const uint8_t* __restrict__ amap,
                                               uint8_t* __restrict__ idxo,
                                               uint8_t* __restrict__ pco) {
    __shared__ float Sl[C_ * 121];
    __shared__ float Tl[C_ * K15_];
    for (int i = threadIdx.x; i < C_ * 120; i += 256) {
        int c = i / 120;
        int r = i - c * 120;
        Sl[c * 121 + r] = S[i];
    }
    for (int i = threadIdx.x; i < C_ * K15_; i += 256) Tl[i] = T[i];
    __syncthreads();

    int gid = blockIdx.x * 256 + threadIdx.x;
    int b = gid >> 6;
    int c = gid & 63;

    const float4* xr = (const float4*)(x + (size_t)b * 512 + c * 8);
    float4 a0 = xr[0];
    float4 a1 = xr[1];
    double xd[8] = {a0.x, a0.y, a0.z, a0.w, a1.x, a1.y, a1.z, a1.w};

    const float* Sc = &Sl[c * 121];
    const float* Tc = &Tl[c * K15_];

    unsigned code = 0;
#pragma unroll
    for (int k = 0; k < K15_; ++k) {
        double p = -(double)Tc[k];
#pragma unroll
        for (int d = 0; d < D_; ++d) p = fma(xd[d], (double)Sc[d * K15_ + k], p);
        code |= (p > 0.0) ? (1u << k) : 0u;
    }
    unsigned idx = amap[code];
    idxo[gid] = (uint8_t)idx;

    unsigned other = (unsigned)__shfl_down((int)idx, 1);
    if (!(c & 1)) pco[b * 32 + (c >> 1)] = (uint8_t)((idx << 4) | other);
}

// ---------------------------------------------------------------------------
// Kernel 3: pair table (fp16): P[p][t0*16+t1][j] = LUT[2p][t0][j]+LUT[2p+1][t1][j]
// One thread per 8 halfs (16B store).
// ---------------------------------------------------------------------------
__global__ __launch_bounds__(256) void k_pairs(const float* __restrict__ LUT,
                                               _Float16* __restrict__ P) {
    int gid = blockIdx.x * 256 + threadIdx.x;  // over half8 chunks
    int j8 = gid & 63;
    int q = (gid >> 6) & 255;
    int p = gid >> 14;
    const float* u = LUT + (size_t)((p * 2) * 16 + (q >> 4)) * 512 + j8 * 8;
    const float* v = LUT + (size_t)((p * 2 + 1) * 16 + (q & 15)) * 512 + j8 * 8;
    float4 u0 = ((const float4*)u)[0];
    float4 u1 = ((const float4*)u)[1];
    float4 v0 = ((const float4*)v)[0];
    float4 v1 = ((const float4*)v)[1];
    half8 w;
    w[0] = (_Float16)(u0.x + v0.x);
    w[1] = (_Float16)(u0.y + v0.y);
    w[2] = (_Float16)(u0.z + v0.z);
    w[3] = (_Float16)(u0.w + v0.w);
    w[4] = (_Float16)(u1.x + v1.x);
    w[5] = (_Float16)(u1.y + v1.y);
    w[6] = (_Float16)(u1.z + v1.z);
    w[7] = (_Float16)(u1.w + v1.w);
    *(half8*)(P + (size_t)gid * 8) = w;
}

// ---------------------------------------------------------------------------
// Kernel 4: out[b][:] = sum over 32 pairs of P[p][pc[b][p]][:]
// Block = 256 threads = 4 waves; wave w handles rows b0+8w..b0+8w+7 (32 rows
// per block). jt = lane covers the 512-wide row as 8 halfs (16B) per lane.
// PAIRS OUTER, rows inner: each block sweeps the 8.4 MB table exactly once,
// all 1024 co-resident blocks in lockstep -> live window ~0.5 MB per XCD L2.
// ---------------------------------------------------------------------------
__global__ __launch_bounds__(256) void k_main2(const uint8_t* __restrict__ pc,
                                               const _Float16* __restrict__ P,
                                               float* __restrict__ out) {
    __shared__ uint8_t pcs[1024];  // 32 rows x 32 pair codes
    int b0 = blockIdx.x * 32;
    ((uint32_t*)pcs)[threadIdx.x] =
        ((const uint32_t*)(pc + (size_t)b0 * 32))[threadIdx.x];
    __syncthreads();

    int jt = threadIdx.x & 63;
    int sub = threadIdx.x >> 6;  // wave id = row group

    float acc[8][8];
#pragma unroll
    for (int r = 0; r < 8; ++r)
#pragma unroll
        for (int e = 0; e < 8; ++e) acc[r][e] = 0.f;

    const _Float16* Pj = P + jt * 8;
    const uint8_t* crb = pcs + sub * 8 * 32;
    for (int p = 0; p < 32; ++p) {
        const _Float16* Pp = Pj + ((size_t)p << 17);  // p*256*512 halfs
        const uint8_t* cr = crb + p;
#pragma unroll
        for (int r = 0; r < 8; ++r) {
            int code = cr[r * 32];
            half8 v = *(const half8*)(Pp + ((size_t)code << 9));  // code*512
#pragma unroll
            for (int e = 0; e < 8; ++e) acc[r][e] += (float)v[e];
        }
    }

#pragma unroll
    for (int r = 0; r < 8; ++r) {
        float* o = out + ((size_t)(b0 + sub * 8 + r)) * 512 + jt * 8;
        float4 w0;
        w0.x = acc[r][0]; w0.y = acc[r][1]; w0.z = acc[r][2]; w0.w = acc[r][3];
        float4 w1;
        w1.x = acc[r][4]; w1.y = acc[r][5]; w1.z = acc[r][6]; w1.w = acc[r][7];
        ((float4*)o)[0] = w0;
        ((float4*)o)[1] = w1;
    }
}

// Fallback (small ws): direct 64-channel gather from fp32 LUT.
__global__ __launch_bounds__(256) void k_main_direct(const uint8_t* __restrict__ idx,
                                                     const float* __restrict__ LUT,
                                                     float* __restrict__ out) {
    int j4 = threadIdx.x & 127;
    int sub = threadIdx.x >> 7;
    int b0 = blockIdx.x * 16 + sub * 8;
    const float4* L4 = (const float4*)LUT;
    for (int r = 0; r < 8; ++r) {
        int b = b0 + r;
        const uint32_t* iw = (const uint32_t*)(idx + (size_t)b * 64);
        float4 acc;
        acc.x = 0.f; acc.y = 0.f; acc.z = 0.f; acc.w = 0.f;
#pragma unroll
        for (int i = 0; i < 16; ++i) {
            uint32_t w = __builtin_amdgcn_readfirstlane(iw[i]);
#pragma unroll
            for (int t = 0; t < 4; ++t) {
                int c = i * 4 + t;
                uint32_t codev = (w >> (8 * t)) & 0xFu;
                float4 v = L4[(size_t)(c * 16 + codev) * 128 + j4];
                acc.x += v.x; acc.y += v.y; acc.z += v.z; acc.w += v.w;
            }
        }
        ((float4*)(out + (size_t)b * 512))[j4] = acc;
    }
}

extern "C" void kernel_launch(void* const* d_in, const int* in_sizes, int n_in,
                              void* d_out, int out_size, void* d_ws, size_t ws_size,
                              hipStream_t stream) {
    const float* x   = (const float*)d_in[0];
    const float* S   = (const float*)d_in[1];
    const float* H   = (const float*)d_in[2];
    const float* T   = (const float*)d_in[3];
    const float* LUT = (const float*)d_in[4];
    float* out = (float*)d_out;

    uint8_t* ws = (uint8_t*)d_ws;
    uint8_t* amap = ws + AMAP_OFF;
    uint8_t* idxb = ws + IDX_OFF;
    uint8_t* pcb  = ws + PC_OFF;
    _Float16* P   = (_Float16*)(ws + PTAB_OFF);

    bool use_pairs = ws_size >= WS_NEED;

    hipLaunchKernelGGL(k_amap, dim3(32768 / 256), dim3(256), 0, stream, H, amap);
    if (use_pairs) {
        // 32*256*512 halfs / 8 per thread / 256 per block = 2048 blocks
        hipLaunchKernelGGL(k_pairs, dim3(2048), dim3(256), 0, stream, LUT, P);
    }
    hipLaunchKernelGGL(k_codes, dim3((B_ * C_) / 256), dim3(256), 0, stream,
                       x, S, T, amap, idxb, pcb);
    if (use_pairs) {
        hipLaunchKernelGGL(k_main2, dim3(B_ / 32), dim3(256), 0, stream,
                           pcb, P, out);
    } else {
        hipLaunchKernelGGL(k_main_direct, dim3(B_ / 16), dim3(256), 0, stream,
                           idxb, LUT, out);
    }
}